// Round 8
// baseline (3728.600 us; speedup 1.0000x reference)
//
#include <hip/hip_runtime.h>

// FullAttention: O[b,l,h,d] = softmax_s( scale * Q[b,l,h,:]·K[b,s,h,:] ) @ V[b,s,h,:]
// B=4, L=S=2048, H=8, E=D=64, fp32 in/out, bf16 MFMA compute.
// R8: BARRIER-FREE inner loop. Prep pass stores bf16 K linear [b][h][s][e] and
//     V transposed [b][h][d][S]; every MFMA fragment is a direct 16B
//     global_load_dwordx4 (L1/L2-served) -> no LDS staging, no __syncthreads,
//     no vmcnt(0) convoy. K register-prefetched 1 tile ahead; V loads issue at
//     iter start, consumed after softmax. Keeps max-free softmax + register
//     C->B P-transform (validated R5-R7) + split-S (2) with combine.

#define B_ 4
#define L_ 2048
#define S_ 2048
#define H_ 8

#define NUMSZ (B_ * L_ * H_ * 64)   // 4194304 floats
#define LSZ (B_ * L_ * H_)          // 65536 floats
#define KVELEM (B_ * H_ * S_ * 64)  // 4194304 bf16 per buffer

typedef __attribute__((ext_vector_type(8))) __bf16 bf16x8;
typedef __attribute__((ext_vector_type(4))) __bf16 bf16x4;
typedef __attribute__((ext_vector_type(16))) float floatx16;

union BF4U { bf16x4 v; uint2 u; };
union BF8U { bf16x8 v; uint4 u; };

__device__ __forceinline__ bf16x8 cvt8(float4 a, float4 b) {
  bf16x8 r;
  r[0] = (__bf16)a.x; r[1] = (__bf16)a.y; r[2] = (__bf16)a.z; r[3] = (__bf16)a.w;
  r[4] = (__bf16)b.x; r[5] = (__bf16)b.y; r[6] = (__bf16)b.z; r[7] = (__bf16)b.w;
  return r;
}

// ---- prep A: K fp32 [b][s][h][e] -> bf16 linear [b][h][s][e]
__global__ __launch_bounds__(256) void prepk_kernel(const float* __restrict__ K,
                                                    __bf16* __restrict__ Kb) {
  const int g = blockIdx.x * 256 + threadIdx.x;  // one 8-elem chunk each
  const int e8 = g & 7;
  const int s = (g >> 3) & (S_ - 1);
  const int h = (g >> 14) & 7;
  const int b = g >> 17;
  const float* src = K + (((size_t)(b * S_ + s) * H_ + h) * 64 + e8 * 8);
  float4 a = *(const float4*)src;
  float4 bb = *(const float4*)(src + 4);
  *(bf16x8*)(Kb + ((size_t)(b * H_ + h) * S_ + s) * 64 + e8 * 8) = cvt8(a, bb);
}

// ---- prep B: V fp32 [b][s][h][d] -> bf16 transposed [b][h][d][S]
__global__ __launch_bounds__(256) void prepv_kernel(const float* __restrict__ V,
                                                    __bf16* __restrict__ Vb) {
  __shared__ float Vs[32 * 64];
  const int bid = blockIdx.x;  // (b*8+h)*64 + tile
  const int tile = bid & 63;
  const int h = (bid >> 6) & 7;
  const int b = bid >> 9;
  const int i = threadIdx.x;
  {
    const int s = i >> 3, d0 = (i & 7) * 8;
    const float* src = V + (((size_t)(b * S_ + tile * 32 + s) * H_ + h) * 64 + d0);
    float4 a = *(const float4*)src;
    float4 bb = *(const float4*)(src + 4);
    *(float4*)&Vs[s * 64 + d0] = a;
    *(float4*)&Vs[s * 64 + d0 + 4] = bb;
  }
  __syncthreads();
  {
    const int d = i & 63, s8 = i >> 6;  // thread: 8 s-values of row d
    BF8U o;
#pragma unroll
    for (int j = 0; j < 8; ++j) o.v[j] = (__bf16)Vs[(s8 * 8 + j) * 64 + d];
    *(bf16x8*)(Vb + ((size_t)(b * H_ + h) * 64 + d) * S_ + tile * 32 + s8 * 8) = o.v;
  }
}

__global__ __launch_bounds__(256, 3) void attn_kernel(const float* __restrict__ Q,
                                                      const __bf16* __restrict__ Kb,
                                                      const __bf16* __restrict__ Vb,
                                                      float* __restrict__ O,
                                                      float* __restrict__ num_ws,
                                                      float* __restrict__ l_ws,
                                                      int splits) {
  const int tid = threadIdx.x;
  const int lane = tid & 63;
  const int wave = tid >> 6;
  const int q32 = lane & 31;  // q column in both QK and PV outputs; s-row in QK A
  const int h32 = lane >> 5;

  const int bid = blockIdx.x;
  const int qb = bid & 15;
  const int h = (bid >> 4) & 7;
  const int b = (bid >> 7) & 3;
  const int split = bid >> 9;

  const int NT = (S_ / 32) / splits;
  const int ts0 = split * NT;

  // ---- Q fragments (B-operand: n=q32, k=h32*8+j), scale*log2e folded
  const float qscale = 0.125f * 1.44269504088896340736f;
  const int qrow = qb * 128 + wave * 32 + q32;
  const float* qp = Q + ((size_t)(b * L_ + qrow) * H_ + h) * 64;
  bf16x8 qf[4];
#pragma unroll
  for (int c = 0; c < 4; ++c) {
    const float* p = qp + c * 16 + h32 * 8;
    float4 a = *(const float4*)p;
    float4 bb = *(const float4*)(p + 4);
    float t[8] = {a.x, a.y, a.z, a.w, bb.x, bb.y, bb.z, bb.w};
#pragma unroll
    for (int j = 0; j < 8; ++j) qf[c][j] = (__bf16)(t[j] * qscale);
  }

  // ---- per-lane base pointers into prepped buffers
  const __bf16* Kbh = Kb + (size_t)(b * H_ + h) * S_ * 64;
  const __bf16* Vbh = Vb + (size_t)(b * H_ + h) * 64 * S_;
  const __bf16* kp = Kbh + q32 * 64 + h32 * 8;               // + ts*2048 + c*16
  const __bf16* vp0 = Vbh + (size_t)q32 * S_ + h32 * 8;      // d-tile 0 row
  const __bf16* vp1 = Vbh + (size_t)(32 + q32) * S_ + h32 * 8;

  // ---- state
  float l = 0.0f;
  floatx16 ot[2];
#pragma unroll
  for (int r = 0; r < 16; ++r) { ot[0][r] = 0.f; ot[1][r] = 0.f; }

  // ---- K prefetch (2-deep register buffer)
  bf16x8 kbuf[2][4];
#pragma unroll
  for (int c = 0; c < 4; ++c)
    kbuf[0][c] = *(const bf16x8*)(kp + (size_t)ts0 * 2048 + c * 16);

  for (int t = 0; t < NT; ++t) {
    const int cur = t & 1;
    const size_t voff = (size_t)(ts0 + t) * 32;

    // V loads for this tile — consumed after QK+softmax (latency self-hidden)
    bf16x8 v00 = *(const bf16x8*)(vp0 + voff);
    bf16x8 v01 = *(const bf16x8*)(vp1 + voff);
    bf16x8 v10 = *(const bf16x8*)(vp0 + voff + 16);
    bf16x8 v11 = *(const bf16x8*)(vp1 + voff + 16);

    // K prefetch for t+1
    if (t + 1 < NT) {
      const size_t knext = (size_t)(ts0 + t + 1) * 2048;
#pragma unroll
      for (int c = 0; c < 4; ++c)
        kbuf[cur ^ 1][c] = *(const bf16x8*)(kp + knext + c * 16);
    }

    // ---- QK: D[s 32][q 32] = K(32s x 64e) x Q^T
    floatx16 sc;
#pragma unroll
    for (int r = 0; r < 16; ++r) sc[r] = 0.f;
#pragma unroll
    for (int c = 0; c < 4; ++c)
      sc = __builtin_amdgcn_mfma_f32_32x32x16_bf16(kbuf[cur][c], qf[c], sc, 0, 0, 0);

    // ---- max-free softmax + in-register C->B transform (validated R5-R7)
    BF4U pg[4];
#pragma unroll
    for (int g = 0; g < 4; ++g) {
      float p0 = __builtin_amdgcn_exp2f(sc[4 * g + 0]);
      float p1 = __builtin_amdgcn_exp2f(sc[4 * g + 1]);
      float p2 = __builtin_amdgcn_exp2f(sc[4 * g + 2]);
      float p3 = __builtin_amdgcn_exp2f(sc[4 * g + 3]);
      l += (p0 + p1) + (p2 + p3);
      pg[g].v = (bf16x4){(__bf16)p0, (__bf16)p1, (__bf16)p2, (__bf16)p3};
    }
    uint2 sendA = h32 ? pg[0].u : pg[1].u;
    uint2 sendB = h32 ? pg[2].u : pg[3].u;
    uint2 recvA, recvB;
    recvA.x = __shfl_xor((int)sendA.x, 32);
    recvA.y = __shfl_xor((int)sendA.y, 32);
    recvB.x = __shfl_xor((int)sendB.x, 32);
    recvB.y = __shfl_xor((int)sendB.y, 32);
    BF8U pB0, pB1;
    if (h32 == 0) {
      pB0.u = (uint4){pg[0].u.x, pg[0].u.y, recvA.x, recvA.y};
      pB1.u = (uint4){pg[2].u.x, pg[2].u.y, recvB.x, recvB.y};
    } else {
      pB0.u = (uint4){recvA.x, recvA.y, pg[1].u.x, pg[1].u.y};
      pB1.u = (uint4){recvB.x, recvB.y, pg[3].u.x, pg[3].u.y};
    }

    // ---- PV: D[d 64][q 32] += Vt(64d x 32s) x P(32s x 32q)
    ot[0] = __builtin_amdgcn_mfma_f32_32x32x16_bf16(v00, pB0.v, ot[0], 0, 0, 0);
    ot[1] = __builtin_amdgcn_mfma_f32_32x32x16_bf16(v01, pB0.v, ot[1], 0, 0, 0);
    ot[0] = __builtin_amdgcn_mfma_f32_32x32x16_bf16(v10, pB1.v, ot[0], 0, 0, 0);
    ot[1] = __builtin_amdgcn_mfma_f32_32x32x16_bf16(v11, pB1.v, ot[1], 0, 0, 0);
  }

  // ---- epilogue
  l += __shfl_xor(l, 32);
  if (splits == 1) {
    const float inv = 1.0f / l;
    float* orow = O + ((size_t)(b * L_ + qrow) * H_ + h) * 64;
#pragma unroll
    for (int dt = 0; dt < 2; ++dt)
#pragma unroll
      for (int g = 0; g < 4; ++g) {
        float4 v = {ot[dt][4 * g + 0] * inv, ot[dt][4 * g + 1] * inv,
                    ot[dt][4 * g + 2] * inv, ot[dt][4 * g + 3] * inv};
        *(float4*)(orow + dt * 32 + g * 8 + h32 * 4) = v;
      }
  } else {
    float* nrow = num_ws + (size_t)split * NUMSZ + ((size_t)(b * L_ + qrow) * H_ + h) * 64;
#pragma unroll
    for (int dt = 0; dt < 2; ++dt)
#pragma unroll
      for (int g = 0; g < 4; ++g) {
        float4 v = {ot[dt][4 * g + 0], ot[dt][4 * g + 1], ot[dt][4 * g + 2],
                    ot[dt][4 * g + 3]};
        *(float4*)(nrow + dt * 32 + g * 8 + h32 * 4) = v;
      }
    if (h32 == 0) l_ws[(size_t)split * LSZ + (size_t)(b * L_ + qrow) * H_ + h] = l;
  }
}

__global__ __launch_bounds__(256) void combine_kernel(const float* __restrict__ num_ws,
                                                      const float* __restrict__ l_ws,
                                                      float* __restrict__ O, int splits) {
  const size_t i4 = ((size_t)blockIdx.x * 256 + threadIdx.x) * 4;
  float4 acc = {0.f, 0.f, 0.f, 0.f};
  float lt = 0.f;
  for (int s = 0; s < splits; ++s) {  // fixed order -> deterministic
    float4 v = *(const float4*)(num_ws + (size_t)s * NUMSZ + i4);
    acc.x += v.x; acc.y += v.y; acc.z += v.z; acc.w += v.w;
    lt += l_ws[(size_t)s * LSZ + (i4 >> 6)];
  }
  const float inv = 1.0f / lt;
  float4 o = {acc.x * inv, acc.y * inv, acc.z * inv, acc.w * inv};
  *(float4*)(O + i4) = o;
}

extern "C" void kernel_launch(void* const* d_in, const int* in_sizes, int n_in,
                              void* d_out, int out_size, void* d_ws, size_t ws_size,
                              hipStream_t stream) {
  const float* Q = (const float*)d_in[0];
  const float* K = (const float*)d_in[1];
  const float* V = (const float*)d_in[2];
  float* O = (float*)d_out;

  __bf16* Kb = (__bf16*)d_ws;
  __bf16* Vb = Kb + KVELEM;
  float* num_ws = (float*)(Vb + KVELEM);
  const size_t base = (size_t)2 * KVELEM * sizeof(__bf16);
  const size_t per_split = ((size_t)NUMSZ + (size_t)LSZ) * sizeof(float);
  int splits = 1;
  if (ws_size >= base + 2 * per_split) splits = 2;  // 1024 blocks, modest combine cost
  float* l_ws = num_ws + (size_t)splits * NUMSZ;

  prepk_kernel<<<KVELEM / 8 / 256, 256, 0, stream>>>(K, Kb);
  prepv_kernel<<<B_ * H_ * 64, 256, 0, stream>>>(V, Vb);
  dim3 grid(B_ * H_ * (L_ / 128) * splits);
  attn_kernel<<<grid, 256, 0, stream>>>(Q, Kb, Vb, O, num_ws, l_ws, splits);
  if (splits > 1) {
    combine_kernel<<<NUMSZ / 4 / 256, 256, 0, stream>>>(num_ws, l_ws, O, splits);
  }
}

// Round 9
// 145.364 us; speedup vs baseline: 25.6501x; 25.6501x over previous
//
#include <hip/hip_runtime.h>

// FullAttention: O[b,l,h,d] = softmax_s( scale * Q[b,l,h,:]·K[b,s,h,:] ) @ V[b,s,h,:]
// B=4, L=S=2048, H=8, E=D=64, fp32 in/out, bf16 MFMA compute.
// R9: revert to R7 LDS+async skeleton (R8's direct global fragments = uncoalesced
//     disaster). NEW: 64 q per wave (two 32-q groups). K/V fragments are
//     q-independent -> one fragment read feeds both groups (per-q LDS traffic
//     halves), and the groups' MFMA/VALU phases are independent -> intra-wave
//     cross-pipe overlap. splits=2, grid 512 (exactly 2 blocks/CU),
//     launch_bounds(256,2) for the ~175-VGPR footprint.

#define B_ 4
#define L_ 2048
#define S_ 2048
#define H_ 8

#define NUMSZ (B_ * L_ * H_ * 64)   // 4194304 floats
#define LSZ (B_ * L_ * H_)          // 65536 floats
#define KVELEM (B_ * H_ * S_ * 64)  // 4194304 bf16 per buffer
#define TILE_ELEMS 2048             // one 32-s tile = 4 KB

typedef __attribute__((ext_vector_type(8))) __bf16 bf16x8;
typedef __attribute__((ext_vector_type(4))) __bf16 bf16x4;
typedef __attribute__((ext_vector_type(16))) float floatx16;

union BF4U { bf16x4 v; uint2 u; };
union BF8U { bf16x8 v; uint4 u; };

__device__ __forceinline__ void async_load16(const void* g, void* l) {
  __builtin_amdgcn_global_load_lds(
      (const __attribute__((address_space(1))) unsigned int*)g,
      (__attribute__((address_space(3))) unsigned int*)l, 16, 0, 0);
}

__device__ __forceinline__ bf16x8 cvt8(float4 a, float4 b) {
  bf16x8 r;
  r[0] = (__bf16)a.x; r[1] = (__bf16)a.y; r[2] = (__bf16)a.z; r[3] = (__bf16)a.w;
  r[4] = (__bf16)b.x; r[5] = (__bf16)b.y; r[6] = (__bf16)b.z; r[7] = (__bf16)b.w;
  return r;
}

// max-free softmax on one 32x32 score block + in-register C->B transform
// (validated R5-R7). Outputs the two PV B-fragments (s-chunks 0,1).
__device__ __forceinline__ void softmax_pb(const floatx16& sc, int h32, float& l,
                                           bf16x8& pB0v, bf16x8& pB1v) {
  BF4U pg[4];
#pragma unroll
  for (int g = 0; g < 4; ++g) {
    float p0 = __builtin_amdgcn_exp2f(sc[4 * g + 0]);
    float p1 = __builtin_amdgcn_exp2f(sc[4 * g + 1]);
    float p2 = __builtin_amdgcn_exp2f(sc[4 * g + 2]);
    float p3 = __builtin_amdgcn_exp2f(sc[4 * g + 3]);
    l += (p0 + p1) + (p2 + p3);
    pg[g].v = (bf16x4){(__bf16)p0, (__bf16)p1, (__bf16)p2, (__bf16)p3};
  }
  uint2 sendA = h32 ? pg[0].u : pg[1].u;
  uint2 sendB = h32 ? pg[2].u : pg[3].u;
  uint2 recvA, recvB;
  recvA.x = __shfl_xor((int)sendA.x, 32);
  recvA.y = __shfl_xor((int)sendA.y, 32);
  recvB.x = __shfl_xor((int)sendB.x, 32);
  recvB.y = __shfl_xor((int)sendB.y, 32);
  BF8U pB0, pB1;
  if (h32 == 0) {
    pB0.u = (uint4){pg[0].u.x, pg[0].u.y, recvA.x, recvA.y};
    pB1.u = (uint4){pg[2].u.x, pg[2].u.y, recvB.x, recvB.y};
  } else {
    pB0.u = (uint4){recvA.x, recvA.y, pg[1].u.x, pg[1].u.y};
    pB1.u = (uint4){recvB.x, recvB.y, pg[3].u.x, pg[3].u.y};
  }
  pB0v = pB0.v;
  pB1v = pB1.v;
}

// ---- pre-pass (unchanged from R6/R7): K,V fp32 -> bf16 swizzled 4KB tiles.
__global__ __launch_bounds__(256) void prep_kernel(const float* __restrict__ K,
                                                   const float* __restrict__ V,
                                                   __bf16* __restrict__ Kb,
                                                   __bf16* __restrict__ Vb) {
  __shared__ float Vs[32 * 64];
  const int bid = blockIdx.x;  // (b*8 + h)*64 + tile
  const int tile = bid & 63;
  const int h = (bid >> 6) & 7;
  const int b = bid >> 9;
  const int s0 = tile * 32;
  const int i = threadIdx.x;

  {
    const int s = i >> 3, cp = i & 7;
    const int e0 = 8 * (cp ^ (s & 7));
    const float* src = K + (((size_t)(b * S_ + s0 + s) * H_ + h) * 64 + e0);
    float4 a = *(const float4*)src;
    float4 bb = *(const float4*)(src + 4);
    *(bf16x8*)(Kb + (size_t)bid * TILE_ELEMS + i * 8) = cvt8(a, bb);
  }
  {
    const int s = i >> 3, d0 = (i & 7) * 8;
    const float* src = V + (((size_t)(b * S_ + s0 + s) * H_ + h) * 64 + d0);
    float4 a = *(const float4*)src;
    float4 bb = *(const float4*)(src + 4);
    *(float4*)&Vs[s * 64 + d0] = a;
    *(float4*)&Vs[s * 64 + d0 + 4] = bb;
  }
  __syncthreads();
  {
    const int Ll = i >> 3, cp = i & 7;
    const int ci = cp ^ (Ll & 7);
    const int d = 2 * Ll + (ci >> 2);
    const int ch = ci & 3;
    BF8U o;
#pragma unroll
    for (int j = 0; j < 8; ++j) o.v[j] = (__bf16)Vs[(8 * ch + j) * 64 + d];
    *(bf16x8*)(Vb + (size_t)bid * TILE_ELEMS + i * 8) = o.v;
  }
}

__global__ __launch_bounds__(256, 2) void attn_kernel(const float* __restrict__ Q,
                                                      const __bf16* __restrict__ Kb,
                                                      const __bf16* __restrict__ Vb,
                                                      float* __restrict__ O,
                                                      float* __restrict__ num_ws,
                                                      float* __restrict__ l_ws,
                                                      int splits) {
  __shared__ __align__(16) __bf16 Kt[2][2 * TILE_ELEMS];  // dbuf, two 32-s sub-tiles
  __shared__ __align__(16) __bf16 Vt[2][2 * TILE_ELEMS];

  const int tid = threadIdx.x;
  const int lane = tid & 63;
  const int wave = tid >> 6;
  const int q32 = lane & 31;
  const int h32 = lane >> 5;

  const int bid = blockIdx.x;  // qb(3) | h(3) | b(2) | split
  const int qb = bid & 7;      // 8 q-blocks of 256 rows
  const int h = (bid >> 3) & 7;
  const int b = (bid >> 6) & 3;
  const int split = bid >> 8;

  const int NT2 = (S_ / 32) / splits / 2;  // 64-s iterations
  const int tile0 = split * NT2 * 2;

  // ---- Q fragments for TWO q-groups (B-operand: n=q32, k=h32*8+j)
  const float qscale = 0.125f * 1.44269504088896340736f;
  const int qrow0 = qb * 256 + wave * 64 + q32;  // group g adds g*32
  bf16x8 qf[2][4];
#pragma unroll
  for (int g = 0; g < 2; ++g) {
    const float* qp = Q + ((size_t)(b * L_ + qrow0 + g * 32) * H_ + h) * 64;
#pragma unroll
    for (int c = 0; c < 4; ++c) {
      const float* p = qp + c * 16 + h32 * 8;
      float4 a = *(const float4*)p;
      float4 bb = *(const float4*)(p + 4);
      float t[8] = {a.x, a.y, a.z, a.w, bb.x, bb.y, bb.z, bb.w};
#pragma unroll
      for (int j = 0; j < 8; ++j) qf[g][c][j] = (__bf16)(t[j] * qscale);
    }
  }

  // ---- per-lane swizzled fragment offsets within a 4KB tile (R6 format)
  int koff[4];
#pragma unroll
  for (int c = 0; c < 4; ++c) koff[c] = (q32 * 8 + (((2 * c + h32) ^ (q32 & 7)))) * 8;
  int voff[2][2];
#pragma unroll
  for (int s2 = 0; s2 < 2; ++s2)
#pragma unroll
    for (int dt = 0; dt < 2; ++dt) {
      int dp = dt * 32 + q32;
      int Ll = dp >> 1;
      int ci = (dp & 1) * 4 + 2 * s2 + h32;
      voff[s2][dt] = (Ll * 8 + (ci ^ (Ll & 7))) * 8;
    }

  // ---- state: per-group l and O accumulators
  float l[2] = {0.f, 0.f};
  floatx16 ot[2][2];  // [q-group][d-tile]
#pragma unroll
  for (int g = 0; g < 2; ++g)
#pragma unroll
    for (int r = 0; r < 16; ++r) { ot[g][0][r] = 0.f; ot[g][1][r] = 0.f; }

  const __bf16* KbBH = Kb + (size_t)((b * H_ + h) * 64) * TILE_ELEMS;
  const __bf16* VbBH = Vb + (size_t)((b * H_ + h) * 64) * TILE_ELEMS;
  const int lin8 = (wave * 64 + lane) * 8;

  // ---- prologue: async-stage tiles (tile0, tile0+1) into buf0
#pragma unroll
  for (int st = 0; st < 2; ++st) {
    async_load16(KbBH + (size_t)(tile0 + st) * TILE_ELEMS + lin8,
                 &Kt[0][st * TILE_ELEMS + wave * 512]);
    async_load16(VbBH + (size_t)(tile0 + st) * TILE_ELEMS + lin8,
                 &Vt[0][st * TILE_ELEMS + wave * 512]);
  }

  for (int t = 0; t < NT2; ++t) {
    const int buf = t & 1;
    __syncthreads();  // buf staged; all reads of buf^1 complete

    if (t + 1 < NT2) {
#pragma unroll
      for (int st = 0; st < 2; ++st) {
        async_load16(KbBH + (size_t)(tile0 + 2 * (t + 1) + st) * TILE_ELEMS + lin8,
                     &Kt[buf ^ 1][st * TILE_ELEMS + wave * 512]);
        async_load16(VbBH + (size_t)(tile0 + 2 * (t + 1) + st) * TILE_ELEMS + lin8,
                     &Vt[buf ^ 1][st * TILE_ELEMS + wave * 512]);
      }
    }

#pragma unroll
    for (int sb = 0; sb < 2; ++sb) {
      const __bf16* Kbuf = &Kt[buf][sb * TILE_ELEMS];
      const __bf16* Vbuf = &Vt[buf][sb * TILE_ELEMS];

      // shared K fragments feed BOTH q-groups' QK
      bf16x8 kA[4];
#pragma unroll
      for (int c = 0; c < 4; ++c) kA[c] = *(const bf16x8*)&Kbuf[koff[c]];

      floatx16 sc0, sc1;
#pragma unroll
      for (int r = 0; r < 16; ++r) { sc0[r] = 0.f; sc1[r] = 0.f; }
#pragma unroll
      for (int c = 0; c < 4; ++c)
        sc0 = __builtin_amdgcn_mfma_f32_32x32x16_bf16(kA[c], qf[0][c], sc0, 0, 0, 0);
#pragma unroll
      for (int c = 0; c < 4; ++c)
        sc1 = __builtin_amdgcn_mfma_f32_32x32x16_bf16(kA[c], qf[1][c], sc1, 0, 0, 0);

      // group-0 softmax overlaps group-1 QK (independent); then vice versa
      bf16x8 p00, p01, p10, p11;
      softmax_pb(sc0, h32, l[0], p00, p01);
      softmax_pb(sc1, h32, l[1], p10, p11);

      // shared V fragments feed BOTH q-groups' PV
      bf16x8 vA[4];  // [s2*2 + dt]
      vA[0] = *(const bf16x8*)&Vbuf[voff[0][0]];
      vA[1] = *(const bf16x8*)&Vbuf[voff[0][1]];
      vA[2] = *(const bf16x8*)&Vbuf[voff[1][0]];
      vA[3] = *(const bf16x8*)&Vbuf[voff[1][1]];
      ot[0][0] = __builtin_amdgcn_mfma_f32_32x32x16_bf16(vA[0], p00, ot[0][0], 0, 0, 0);
      ot[0][1] = __builtin_amdgcn_mfma_f32_32x32x16_bf16(vA[1], p00, ot[0][1], 0, 0, 0);
      ot[1][0] = __builtin_amdgcn_mfma_f32_32x32x16_bf16(vA[0], p10, ot[1][0], 0, 0, 0);
      ot[1][1] = __builtin_amdgcn_mfma_f32_32x32x16_bf16(vA[1], p10, ot[1][1], 0, 0, 0);
      ot[0][0] = __builtin_amdgcn_mfma_f32_32x32x16_bf16(vA[2], p01, ot[0][0], 0, 0, 0);
      ot[0][1] = __builtin_amdgcn_mfma_f32_32x32x16_bf16(vA[3], p01, ot[0][1], 0, 0, 0);
      ot[1][0] = __builtin_amdgcn_mfma_f32_32x32x16_bf16(vA[2], p11, ot[1][0], 0, 0, 0);
      ot[1][1] = __builtin_amdgcn_mfma_f32_32x32x16_bf16(vA[3], p11, ot[1][1], 0, 0, 0);
    }
  }

  // ---- epilogue (per q-group)
#pragma unroll
  for (int g = 0; g < 2; ++g) {
    float lg = l[g] + __shfl_xor(l[g], 32);
    const int qrow = qrow0 + g * 32;
    if (splits == 1) {
      const float inv = 1.0f / lg;
      float* orow = O + ((size_t)(b * L_ + qrow) * H_ + h) * 64;
#pragma unroll
      for (int dt = 0; dt < 2; ++dt)
#pragma unroll
        for (int gg = 0; gg < 4; ++gg) {
          float4 v = {ot[g][dt][4 * gg + 0] * inv, ot[g][dt][4 * gg + 1] * inv,
                      ot[g][dt][4 * gg + 2] * inv, ot[g][dt][4 * gg + 3] * inv};
          *(float4*)(orow + dt * 32 + gg * 8 + h32 * 4) = v;
        }
    } else {
      float* nrow =
          num_ws + (size_t)split * NUMSZ + ((size_t)(b * L_ + qrow) * H_ + h) * 64;
#pragma unroll
      for (int dt = 0; dt < 2; ++dt)
#pragma unroll
        for (int gg = 0; gg < 4; ++gg) {
          float4 v = {ot[g][dt][4 * gg + 0], ot[g][dt][4 * gg + 1],
                      ot[g][dt][4 * gg + 2], ot[g][dt][4 * gg + 3]};
          *(float4*)(nrow + dt * 32 + gg * 8 + h32 * 4) = v;
        }
      if (h32 == 0)
        l_ws[(size_t)split * LSZ + (size_t)(b * L_ + qrow) * H_ + h] = lg;
    }
  }
}

__global__ __launch_bounds__(256) void combine_kernel(const float* __restrict__ num_ws,
                                                      const float* __restrict__ l_ws,
                                                      float* __restrict__ O, int splits) {
  const size_t i4 = ((size_t)blockIdx.x * 256 + threadIdx.x) * 4;
  float4 acc = {0.f, 0.f, 0.f, 0.f};
  float lt = 0.f;
  for (int s = 0; s < splits; ++s) {  // fixed order -> deterministic
    float4 v = *(const float4*)(num_ws + (size_t)s * NUMSZ + i4);
    acc.x += v.x; acc.y += v.y; acc.z += v.z; acc.w += v.w;
    lt += l_ws[(size_t)s * LSZ + (i4 >> 6)];
  }
  const float inv = 1.0f / lt;
  float4 o = {acc.x * inv, acc.y * inv, acc.z * inv, acc.w * inv};
  *(float4*)(O + i4) = o;
}

extern "C" void kernel_launch(void* const* d_in, const int* in_sizes, int n_in,
                              void* d_out, int out_size, void* d_ws, size_t ws_size,
                              hipStream_t stream) {
  const float* Q = (const float*)d_in[0];
  const float* K = (const float*)d_in[1];
  const float* V = (const float*)d_in[2];
  float* O = (float*)d_out;

  __bf16* Kb = (__bf16*)d_ws;
  __bf16* Vb = Kb + KVELEM;
  float* num_ws = (float*)(Vb + KVELEM);
  const size_t base = (size_t)2 * KVELEM * sizeof(__bf16);
  const size_t per_split = ((size_t)NUMSZ + (size_t)LSZ) * sizeof(float);
  int splits = 1;
  if (ws_size >= base + 2 * per_split) splits = 2;
  float* l_ws = num_ws + (size_t)splits * NUMSZ;

  prep_kernel<<<B_ * H_ * 64, 256, 0, stream>>>(K, V, Kb, Vb);
  dim3 grid(B_ * H_ * (L_ / 256) * splits);  // 512 blocks at splits=2
  attn_kernel<<<grid, 256, 0, stream>>>(Q, Kb, Vb, O, num_ws, l_ws, splits);
  if (splits > 1) {
    combine_kernel<<<NUMSZ / 4 / 256, 256, 0, stream>>>(num_ws, l_ws, O, splits);
  }
}